// Round 1
// 179.048 us; speedup vs baseline: 1.0870x; 1.0870x over previous
//
#include <hip/hip_runtime.h>
#include <hip/hip_bf16.h>

#define SEQ 2048
#define DMODEL 1024
#define NHEADS 16
#define HD 64
#define BATCH 2

typedef short bf16x8 __attribute__((ext_vector_type(8)));
typedef float f32x4 __attribute__((ext_vector_type(4)));
typedef float f32x16 __attribute__((ext_vector_type(16)));

// fp32 -> bf16 (RNE), finite inputs only
static __device__ inline ushort f2bf(float f) {
    unsigned u = __float_as_uint(f);
    return (ushort)((u + 0x7fffu + ((u >> 16) & 1u)) >> 16);
}

// packed pair convert: low 16 = a, high 16 = b (v_cvt_pk_bf16_f32 on gfx950)
static __device__ inline unsigned pk2bf(float a, float b) {
    __hip_bfloat162 h = __float22bfloat162_rn(make_float2(a, b));
    union { __hip_bfloat162 h; unsigned u; } c; c.h = h;
    return c.u;
}

static __device__ inline void async16(const ushort* g, ushort* l) {
    __builtin_amdgcn_global_load_lds((const __attribute__((address_space(1))) void*)g,
                                     (__attribute__((address_space(3))) void*)l, 16, 0, 0);
}

// exchange dst-hi-lanes with src-lo-lanes (v_permlane32_swap_b32)
static __device__ inline void plane32swap(unsigned& a, unsigned& b) {
    asm volatile("v_permlane32_swap_b32 %0, %1" : "+v"(a), "+v"(b));
}

// one launch: convert x and W_qkv fp32 -> bf16
__global__ void cvt2(const float* __restrict__ a, ushort* __restrict__ da, int na,
                     const float* __restrict__ b, ushort* __restrict__ db, int nb) {
    long i = (long)(blockIdx.x * blockDim.x + threadIdx.x) * 4;
    const float* s; ushort* d;
    if (i < na) { s = a + i; d = da + i; }
    else { long j = i - na; if (j >= nb) return; s = b + j; d = db + j; }
    float4 v = *(const float4*)s;
    ushort4 o; o.x = f2bf(v.x); o.y = f2bf(v.y); o.z = f2bf(v.z); o.w = f2bf(v.w);
    *(ushort4*)d = o;
}

// LDS: staging (2x16KB) and epilogue C-tile (32KB) share the same 32KB block
union GemmSmem {
    struct { ushort A[128 * 64]; ushort B[128 * 64]; } st;
    ushort C[128 * 128];   // bf16 C-tile, XOR-swizzled: phys_col = col ^ (8*(row&7))
};

// qkv = x @ W^T. m97 K-loop (unpadded LDS, global_load_lds w=16).
__global__ __launch_bounds__(256) void qkv_gemm(
        const ushort* __restrict__ X, const ushort* __restrict__ W,
        ushort* __restrict__ Qd, ushort* __restrict__ Kd, ushort* __restrict__ Vd) {
    __shared__ GemmSmem sm;
    const int t = threadIdx.x;
    const int lane = t & 63, l15 = lane & 15, quad = lane >> 4;
    const int w = t >> 6, wm = w >> 1, wn = w & 1;
    const int gm = blockIdx.x, gn = blockIdx.y;
    const int srow = t >> 3, scol = (t & 7) * 8;

    f32x4 acc[4][4] = {};

    for (int kt = 0; kt < 16; ++kt) {
        const int k0 = kt * 64;
        __syncthreads();
#pragma unroll
        for (int inst = 0; inst < 4; ++inst) {
            async16(&X[(gm * 128 + inst * 32 + srow) * 1024 + k0 + scol], &sm.st.A[inst * 2048 + t * 8]);
            async16(&W[(gn * 128 + inst * 32 + srow) * 1024 + k0 + scol], &sm.st.B[inst * 2048 + t * 8]);
        }
        __syncthreads();
#pragma unroll
        for (int ks = 0; ks < 2; ++ks) {
            const int kk = ks * 32 + quad * 8;
            bf16x8 af[4], bfr[4];
#pragma unroll
            for (int i = 0; i < 4; ++i) {
                af[i]  = *(const bf16x8*)&sm.st.A[(wm * 64 + i * 16 + l15) * 64 + kk];
                bfr[i] = *(const bf16x8*)&sm.st.B[(wn * 64 + i * 16 + l15) * 64 + kk];
            }
#pragma unroll
            for (int i = 0; i < 4; ++i)
#pragma unroll
                for (int j = 0; j < 4; ++j)
                    acc[i][j] = __builtin_amdgcn_mfma_f32_16x16x32_bf16(af[i], bfr[j], acc[i][j], 0, 0, 0);
        }
    }

    __syncthreads();   // all frag reads done; reuse LDS as C-tile
    const float sc = (gn < 8) ? (0.125f * 1.44269504f) : 1.0f;  // fold softmax scale into Q
#pragma unroll
    for (int i = 0; i < 4; ++i)
#pragma unroll
        for (int reg = 0; reg < 4; ++reg) {
            const int row = wm * 64 + i * 16 + quad * 4 + reg;
            const int sw = (row & 7) * 8;
#pragma unroll
            for (int jp = 0; jp < 4; jp += 2) {
                unsigned u = pk2bf(acc[i][jp][reg] * sc, acc[i][jp + 1][reg] * sc);
                sm.C[row * 128 + ((wn * 64 + jp * 16 + l15) ^ sw)] = (ushort)u;
                sm.C[row * 128 + ((wn * 64 + (jp + 1) * 16 + l15) ^ sw)] = (ushort)(u >> 16);
            }
        }
    __syncthreads();

    const int which = gn >> 3;   // 0=Q 1=K 2=V (uniform per block)
    ushort* dst = (which == 0) ? Qd : ((which == 1) ? Kd : Vd);
    const int rloc = t >> 4, l = t & 15;
#pragma unroll
    for (int pass = 0; pass < 8; ++pass) {
        const int r = pass * 16 + rloc;
        bf16x8 v = *(const bf16x8*)&sm.C[r * 128 + ((l * 8) ^ ((r & 7) * 8))];
        const int ng = gm * 128 + r;
        const int b = ng >> 11, n = ng & 2047;
        const int cl = (gn * 128 + l * 8) & 1023;
        const int h = cl >> 6, hd = cl & 63;
        *(bf16x8*)&dst[(((b * NHEADS + h) * SEQ) + n) * HD + hd] = v;
    }
}

// V [bh][n][hd] -> VT [bh][hd][n], LDS-tiled 64x64
__global__ __launch_bounds__(256) void tr_v(const ushort* __restrict__ src, ushort* __restrict__ dst) {
    __shared__ ushort sT[64][72];
    const int t = threadIdx.x;
    const int bh = blockIdx.y, nt = blockIdx.x;
    const int r0 = t >> 3, c8 = (t & 7) * 8;
    const ushort* sp = src + ((long)bh * SEQ + nt * 64) * HD;
#pragma unroll
    for (int rr = 0; rr < 64; rr += 32)
        *(bf16x8*)&sT[rr + r0][c8] = *(const bf16x8*)&sp[(rr + r0) * HD + c8];
    __syncthreads();
    ushort* dp = dst + (long)bh * HD * SEQ + nt * 64;
#pragma unroll
    for (int rr = 0; rr < 64; rr += 32) {
        const int hd = rr + r0;
        bf16x8 v;
#pragma unroll
        for (int j = 0; j < 8; ++j) v[j] = (short)sT[c8 + j][hd];
        *(bf16x8*)&dp[(long)hd * SEQ + c8] = v;
    }
}

// Flash attention (no-max softmax; logits bounded, scale folded into Q).
// 8 warps x 32 q-rows = 256 q/block; KVBLK=64; swapped QK^T (S^T = K.Q^T) with
// 32x32x16 MFMA so each lane owns a P-row in registers; softmax in-register;
// P->A-frag via cvt_pk + v_permlane32_swap; K/VT double-buffered in LDS via
// global_load_lds with XOR-swizzle (pre-swizzled global source).
__global__ __launch_bounds__(512, 2) void attn_kernel(
        const ushort* __restrict__ Q, const ushort* __restrict__ K,
        const ushort* __restrict__ VT, float* __restrict__ O) {
    __shared__ ushort sK[2][64 * 64];
    __shared__ ushort sVT[2][64 * 64];
    __shared__ float sL[8][32];

    const int t = threadIdx.x;
    const int lane = t & 63, l31 = lane & 31, hi = lane >> 5;
    const int w = t >> 6;

    // XCD swizzle: all 8 q-blocks of one bh land on the same XCD (blocks dispatch
    // round-robin by flat id % 8); each XCD caches 4 bh worth of K/V (2MB) in L2.
    const int flat = blockIdx.y * gridDim.x + blockIdx.x;   // 0..255
    const int qt = (flat >> 3) & 7;
    const int bh = (flat & 7) + ((flat >> 6) << 3);

    const ushort* Qp = Q + ((long)bh * SEQ + qt * 256 + w * 32) * HD;
    const ushort* Kp = K + (long)bh * SEQ * HD;
    const ushort* Vp = VT + (long)bh * HD * SEQ;

    // Q fragments (B operand): lane holds Q[q=l31][k = ks*16 + hi*8 + j]
    bf16x8 bq[4];
#pragma unroll
    for (int ks = 0; ks < 4; ++ks)
        bq[ks] = *(const bf16x8*)&Qp[l31 * HD + ks * 16 + hi * 8];

    // staging: thread t fills LDS row r=t>>3, 16B group (t&7) (linear dest for
    // global_load_lds); XOR-swizzle achieved by pre-swizzling the SOURCE column.
    const int sr = t >> 3;                        // 0..63
    const int scc = ((t & 7) ^ (sr & 7)) * 8;     // swizzled source elem col
    const ushort* gK = Kp + sr * HD + scc;
    const ushort* gV = Vp + (long)sr * SEQ + scc;
    ushort* lK[2] = { &sK[0][t * 8], &sK[1][t * 8] };
    ushort* lV[2] = { &sVT[0][t * 8], &sVT[1][t * 8] };

    f32x16 accO[2] = {};
    float Lp = 0.f;
    const int swz = (l31 & 7) << 3;

    // prologue: stage tile 0 (syncthreads drains vmcnt)
    async16(gK, lK[0]);
    async16(gV, lV[0]);
    __syncthreads();

    for (int kt = 0; kt < 32; ++kt) {
        const int cur = kt & 1;
        if (kt < 31) {      // prefetch next tile into other buffer; lands during compute
            async16(gK + (kt + 1) * 64 * HD, lK[cur ^ 1]);
            async16(gV + (kt + 1) * 64,      lV[cur ^ 1]);
        }
        const ushort* bK = sK[cur];
        const ushort* bV = sVT[cur];

        // QK^T swapped: s[nb] = K-tile(nb) . Q^T ; lane holds P-row q=l31
        f32x16 s[2];
#pragma unroll
        for (int nb = 0; nb < 2; ++nb) {
            f32x16 z = {};
            __builtin_amdgcn_s_setprio(1);
#pragma unroll
            for (int ks = 0; ks < 4; ++ks) {
                bf16x8 ak = *(const bf16x8*)&bK[(nb * 32 + l31) * 64 + ((ks * 16 + hi * 8) ^ swz)];
                z = __builtin_amdgcn_mfma_f32_32x32x16_bf16(ak, bq[ks], z, 0, 0, 0);
            }
            __builtin_amdgcn_s_setprio(0);
            s[nb] = z;
        }

        // in-register softmax: p = exp2(s); L row-sum in-lane; build PV A-frags
        // via cvt_pk pairs + permlane32_swap (dwords land in-order c0..c3).
        bf16x8 pa[4];
#pragma unroll
        for (int nb = 0; nb < 2; ++nb) {
            float p[16];
#pragma unroll
            for (int r = 0; r < 16; ++r) { p[r] = exp2f(s[nb][r]); Lp += p[r]; }
#pragma unroll
            for (int h2 = 0; h2 < 2; ++h2) {
                const int b = 8 * h2;
                unsigned c0 = pk2bf(p[b + 0], p[b + 1]);
                unsigned c1 = pk2bf(p[b + 2], p[b + 3]);
                unsigned c2 = pk2bf(p[b + 4], p[b + 5]);
                unsigned c3 = pk2bf(p[b + 6], p[b + 7]);
                plane32swap(c0, c2);
                plane32swap(c1, c3);
                union { unsigned u[4]; bf16x8 v; } f;
                f.u[0] = c0; f.u[1] = c1; f.u[2] = c2; f.u[3] = c3;
                pa[nb * 2 + h2] = f.v;
            }
        }

        // PV: accO[db] += P . V (B-frags from swizzled VT)
        __builtin_amdgcn_s_setprio(1);
#pragma unroll
        for (int db = 0; db < 2; ++db)
#pragma unroll
            for (int ks = 0; ks < 4; ++ks) {
                bf16x8 vf = *(const bf16x8*)&bV[(db * 32 + l31) * 64 + ((ks * 16 + hi * 8) ^ swz)];
                accO[db] = __builtin_amdgcn_mfma_f32_32x32x16_bf16(pa[ks], vf, accO[db], 0, 0, 0);
            }
        __builtin_amdgcn_s_setprio(0);

        __syncthreads();   // all reads of buf[cur] done; next iter overwrites it
    }

    // combine L halves (lane <-> lane+32 hold complementary kv columns of q=l31)
    unsigned lu = __float_as_uint(Lp), lv = lu;
    plane32swap(lu, lv);
    const float Ltot = __uint_as_float(lu) + __uint_as_float(lv);
    if (hi == 0) sL[w][l31] = Ltot;
    __syncthreads();

    const int b = bh >> 4, h = bh & 15;
    const int qg0 = qt * 256 + w * 32;
#pragma unroll
    for (int r = 0; r < 16; ++r) {
        const int ql = (r & 3) + 8 * (r >> 2) + 4 * hi;   // C-row -> q within warp
        const float inv = 1.0f / sL[w][ql];
        const int row = qg0 + ql;
#pragma unroll
        for (int db = 0; db < 2; ++db)
            O[((long)b * SEQ + row) * DMODEL + h * HD + db * 32 + l31] = accO[db][r] * inv;
    }
}

extern "C" void kernel_launch(void* const* d_in, const int* in_sizes, int n_in,
                              void* d_out, int out_size, void* d_ws, size_t ws_size,
                              hipStream_t stream) {
    const float* x  = (const float*)d_in[0];   // (2, 2048, 1024) fp32
    const float* Wq = (const float*)d_in[1];   // (3072, 1024) fp32
    float* out = (float*)d_out;                // (2, 2048, 1024) fp32

    const int NX = BATCH * SEQ * DMODEL;        // 4194304
    const int NW = 3 * DMODEL * DMODEL;         // 3145728
    const int NQKV = BATCH * NHEADS * SEQ * HD; // 4194304

    ushort* xb = (ushort*)d_ws;
    ushort* wb = xb + NX;
    ushort* q  = wb + NW;
    ushort* k  = q + NQKV;
    ushort* vtmp = k + NQKV;
    ushort* vt = xb;    // xb is dead after the GEMM; alias it for V^T (same size)

    cvt2<<<(NX + NW) / 4 / 256, 256, 0, stream>>>(x, xb, NX, Wq, wb, NW);

    dim3 g1(4096 / 128, 3072 / 128);   // 32 x 24
    qkv_gemm<<<g1, 256, 0, stream>>>(xb, wb, q, k, vtmp);

    dim3 gt(SEQ / 64, BATCH * NHEADS); // 32 x 32
    tr_v<<<gt, 256, 0, stream>>>(vtmp, vt);

    dim3 g2(SEQ / 256, BATCH * NHEADS); // 8 x 32
    attn_kernel<<<g2, 512, 0, stream>>>(q, k, vt, out);
}

// Round 2
// 178.439 us; speedup vs baseline: 1.0907x; 1.0034x over previous
//
#include <hip/hip_runtime.h>
#include <hip/hip_bf16.h>

#define SEQ 2048
#define DMODEL 1024
#define NHEADS 16
#define HD 64
#define BATCH 2

typedef short bf16x8 __attribute__((ext_vector_type(8)));
typedef float f32x4 __attribute__((ext_vector_type(4)));
typedef float f32x16 __attribute__((ext_vector_type(16)));

// fp32 -> bf16 (RNE), finite inputs only
static __device__ inline ushort f2bf(float f) {
    unsigned u = __float_as_uint(f);
    return (ushort)((u + 0x7fffu + ((u >> 16) & 1u)) >> 16);
}

// packed pair convert: low 16 = a, high 16 = b (v_cvt_pk_bf16_f32 on gfx950)
static __device__ inline unsigned pk2bf(float a, float b) {
    __hip_bfloat162 h = __float22bfloat162_rn(make_float2(a, b));
    union { __hip_bfloat162 h; unsigned u; } c; c.h = h;
    return c.u;
}

static __device__ inline void async16(const ushort* g, ushort* l) {
    __builtin_amdgcn_global_load_lds((const __attribute__((address_space(1))) void*)g,
                                     (__attribute__((address_space(3))) void*)l, 16, 0, 0);
}

// exchange dst-hi-lanes with src-lo-lanes (v_permlane32_swap_b32)
static __device__ inline void plane32swap(unsigned& a, unsigned& b) {
    asm volatile("v_permlane32_swap_b32 %0, %1" : "+v"(a), "+v"(b));
}

// one launch: convert x and W_qkv fp32 -> bf16
__global__ void cvt2(const float* __restrict__ a, ushort* __restrict__ da, int na,
                     const float* __restrict__ b, ushort* __restrict__ db, int nb) {
    long i = (long)(blockIdx.x * blockDim.x + threadIdx.x) * 4;
    const float* s; ushort* d;
    if (i < na) { s = a + i; d = da + i; }
    else { long j = i - na; if (j >= nb) return; s = b + j; d = db + j; }
    float4 v = *(const float4*)s;
    ushort4 o; o.x = f2bf(v.x); o.y = f2bf(v.y); o.z = f2bf(v.z); o.w = f2bf(v.w);
    *(ushort4*)d = o;
}

// LDS: staging (2x16KB) and epilogue C-tile (32KB) share the same 32KB block
union GemmSmem {
    struct { ushort A[128 * 64]; ushort B[128 * 64]; } st;
    ushort C[128 * 128];   // bf16 C-tile, XOR-swizzled: phys_col = col ^ (8*(row&7))
};

// qkv = x @ W^T. m97 K-loop (unpadded LDS, global_load_lds w=16).
__global__ __launch_bounds__(256) void qkv_gemm(
        const ushort* __restrict__ X, const ushort* __restrict__ W,
        ushort* __restrict__ Qd, ushort* __restrict__ Kd, ushort* __restrict__ Vd) {
    __shared__ GemmSmem sm;
    const int t = threadIdx.x;
    const int lane = t & 63, l15 = lane & 15, quad = lane >> 4;
    const int w = t >> 6, wm = w >> 1, wn = w & 1;
    const int gm = blockIdx.x, gn = blockIdx.y;
    const int srow = t >> 3, scol = (t & 7) * 8;

    f32x4 acc[4][4] = {};

    for (int kt = 0; kt < 16; ++kt) {
        const int k0 = kt * 64;
        __syncthreads();
#pragma unroll
        for (int inst = 0; inst < 4; ++inst) {
            async16(&X[(gm * 128 + inst * 32 + srow) * 1024 + k0 + scol], &sm.st.A[inst * 2048 + t * 8]);
            async16(&W[(gn * 128 + inst * 32 + srow) * 1024 + k0 + scol], &sm.st.B[inst * 2048 + t * 8]);
        }
        __syncthreads();
#pragma unroll
        for (int ks = 0; ks < 2; ++ks) {
            const int kk = ks * 32 + quad * 8;
            bf16x8 af[4], bfr[4];
#pragma unroll
            for (int i = 0; i < 4; ++i) {
                af[i]  = *(const bf16x8*)&sm.st.A[(wm * 64 + i * 16 + l15) * 64 + kk];
                bfr[i] = *(const bf16x8*)&sm.st.B[(wn * 64 + i * 16 + l15) * 64 + kk];
            }
#pragma unroll
            for (int i = 0; i < 4; ++i)
#pragma unroll
                for (int j = 0; j < 4; ++j)
                    acc[i][j] = __builtin_amdgcn_mfma_f32_16x16x32_bf16(af[i], bfr[j], acc[i][j], 0, 0, 0);
        }
    }

    __syncthreads();   // all frag reads done; reuse LDS as C-tile
    const float sc = (gn < 8) ? (0.125f * 1.44269504f) : 1.0f;  // fold softmax scale into Q
#pragma unroll
    for (int i = 0; i < 4; ++i)
#pragma unroll
        for (int reg = 0; reg < 4; ++reg) {
            const int row = wm * 64 + i * 16 + quad * 4 + reg;
            const int sw = (row & 7) * 8;
#pragma unroll
            for (int jp = 0; jp < 4; jp += 2) {
                unsigned u = pk2bf(acc[i][jp][reg] * sc, acc[i][jp + 1][reg] * sc);
                sm.C[row * 128 + ((wn * 64 + jp * 16 + l15) ^ sw)] = (ushort)u;
                sm.C[row * 128 + ((wn * 64 + (jp + 1) * 16 + l15) ^ sw)] = (ushort)(u >> 16);
            }
        }
    __syncthreads();

    const int which = gn >> 3;   // 0=Q 1=K 2=V (uniform per block)
    ushort* dst = (which == 0) ? Qd : ((which == 1) ? Kd : Vd);
    const int rloc = t >> 4, l = t & 15;
#pragma unroll
    for (int pass = 0; pass < 8; ++pass) {
        const int r = pass * 16 + rloc;
        bf16x8 v = *(const bf16x8*)&sm.C[r * 128 + ((l * 8) ^ ((r & 7) * 8))];
        const int ng = gm * 128 + r;
        const int b = ng >> 11, n = ng & 2047;
        const int cl = (gn * 128 + l * 8) & 1023;
        const int h = cl >> 6, hd = cl & 63;
        *(bf16x8*)&dst[(((b * NHEADS + h) * SEQ) + n) * HD + hd] = v;
    }
}

// V [bh][n][hd] -> VT [bh][hd][n], LDS-tiled 64x64
__global__ __launch_bounds__(256) void tr_v(const ushort* __restrict__ src, ushort* __restrict__ dst) {
    __shared__ ushort sT[64][72];
    const int t = threadIdx.x;
    const int bh = blockIdx.y, nt = blockIdx.x;
    const int r0 = t >> 3, c8 = (t & 7) * 8;
    const ushort* sp = src + ((long)bh * SEQ + nt * 64) * HD;
#pragma unroll
    for (int rr = 0; rr < 64; rr += 32)
        *(bf16x8*)&sT[rr + r0][c8] = *(const bf16x8*)&sp[(rr + r0) * HD + c8];
    __syncthreads();
    ushort* dp = dst + (long)bh * HD * SEQ + nt * 64;
#pragma unroll
    for (int rr = 0; rr < 64; rr += 32) {
        const int hd = rr + r0;
        bf16x8 v;
#pragma unroll
        for (int j = 0; j < 8; ++j) v[j] = (short)sT[c8 + j][hd];
        *(bf16x8*)&dp[(long)hd * SEQ + c8] = v;
    }
}

// Flash attention (no-max softmax; logits bounded, scale folded into Q).
// 4 warps x 32 q-rows = 128 q/block; KVBLK=64; swapped QK^T (S^T = K.Q^T) with
// 32x32x16 MFMA so each lane owns a P-row in registers; softmax in-register;
// P->A-frag via cvt_pk + v_permlane32_swap; K/VT double-buffered in LDS via
// global_load_lds with XOR-swizzle (pre-swizzled global source).
// 2 independent 4-warp workgroups per CU (separate barrier domains) so one
// block's softmax (VALU) overlaps the other's MFMA; launch_bounds(256,2)
// keeps the unified VGPR+AGPR budget at 256/wave (no register shuffle).
__global__ __launch_bounds__(256, 2) void attn_kernel(
        const ushort* __restrict__ Q, const ushort* __restrict__ K,
        const ushort* __restrict__ VT, float* __restrict__ O) {
    __shared__ ushort sK[2][64 * 64];
    __shared__ ushort sVT[2][64 * 64];
    __shared__ float sL[4][32];

    const int t = threadIdx.x;
    const int lane = t & 63, l31 = lane & 31, hi = lane >> 5;
    const int w = t >> 6;

    // XCD swizzle: blocks dispatch round-robin by flat id % 8. Map so all 16
    // q-blocks of one bh share an XCD; each XCD caches 4 bh of K/V (2MB) in L2.
    // f bits: [2:0]=bh-low, [6:3]=qt, [8:7]=bh-high (bijective over 512).
    const int flat = blockIdx.y * gridDim.x + blockIdx.x;   // 0..511
    const int qt = (flat >> 3) & 15;
    const int bh = (flat & 7) + ((flat >> 7) << 3);

    const ushort* Qp = Q + ((long)bh * SEQ + qt * 128 + w * 32) * HD;
    const ushort* Kp = K + (long)bh * SEQ * HD;
    const ushort* Vp = VT + (long)bh * HD * SEQ;

    // Q fragments (B operand): lane holds Q[q=l31][k = ks*16 + hi*8 + j]
    bf16x8 bq[4];
#pragma unroll
    for (int ks = 0; ks < 4; ++ks)
        bq[ks] = *(const bf16x8*)&Qp[l31 * HD + ks * 16 + hi * 8];

    // staging: 256 threads cover rows 0..31 (and +32) x 8 chunk slots; linear
    // LDS dest for global_load_lds; XOR-swizzle via pre-swizzled SOURCE column.
    const int sr = t >> 3;                        // 0..31
    const int scc = ((t & 7) ^ (sr & 7)) * 8;     // swizzled source elem col
    const ushort* gK = Kp + sr * HD + scc;        // row sr; +32*HD for row sr+32
    const ushort* gV = Vp + (long)sr * SEQ + scc; // row sr; +32*SEQ for row sr+32
    ushort* lK[2] = { &sK[0][t * 8], &sK[1][t * 8] };
    ushort* lV[2] = { &sVT[0][t * 8], &sVT[1][t * 8] };

    f32x16 accO[2] = {};
    float Lp = 0.f;
    const int swz = (l31 & 7) << 3;

    // prologue: stage tile 0 (syncthreads drains vmcnt)
    async16(gK, lK[0]);
    async16(gK + 32 * HD, lK[0] + 32 * 64);
    async16(gV, lV[0]);
    async16(gV + 32 * SEQ, lV[0] + 32 * 64);
    __syncthreads();

    for (int kt = 0; kt < 32; ++kt) {
        const int cur = kt & 1;
        if (kt < 31) {      // prefetch next tile into other buffer; lands during compute
            const ushort* nK = gK + (kt + 1) * 64 * HD;
            const ushort* nV = gV + (kt + 1) * 64;
            async16(nK, lK[cur ^ 1]);
            async16(nK + 32 * HD, lK[cur ^ 1] + 32 * 64);
            async16(nV, lV[cur ^ 1]);
            async16(nV + 32 * SEQ, lV[cur ^ 1] + 32 * 64);
        }
        const ushort* bK = sK[cur];
        const ushort* bV = sVT[cur];

        // QK^T swapped: s[nb] = K-tile(nb) . Q^T ; lane holds P-row q=l31
        f32x16 s[2];
#pragma unroll
        for (int nb = 0; nb < 2; ++nb) {
            f32x16 z = {};
            __builtin_amdgcn_s_setprio(1);
#pragma unroll
            for (int ks = 0; ks < 4; ++ks) {
                bf16x8 ak = *(const bf16x8*)&bK[(nb * 32 + l31) * 64 + ((ks * 16 + hi * 8) ^ swz)];
                z = __builtin_amdgcn_mfma_f32_32x32x16_bf16(ak, bq[ks], z, 0, 0, 0);
            }
            __builtin_amdgcn_s_setprio(0);
            s[nb] = z;
        }

        // in-register softmax: p = exp2(s); L row-sum in-lane; build PV A-frags
        // via cvt_pk pairs + permlane32_swap (dwords land in-order c0..c3).
        bf16x8 pa[4];
#pragma unroll
        for (int nb = 0; nb < 2; ++nb) {
            float p[16];
#pragma unroll
            for (int r = 0; r < 16; ++r) { p[r] = exp2f(s[nb][r]); Lp += p[r]; }
#pragma unroll
            for (int h2 = 0; h2 < 2; ++h2) {
                const int b = 8 * h2;
                unsigned c0 = pk2bf(p[b + 0], p[b + 1]);
                unsigned c1 = pk2bf(p[b + 2], p[b + 3]);
                unsigned c2 = pk2bf(p[b + 4], p[b + 5]);
                unsigned c3 = pk2bf(p[b + 6], p[b + 7]);
                plane32swap(c0, c2);
                plane32swap(c1, c3);
                union { unsigned u[4]; bf16x8 v; } f;
                f.u[0] = c0; f.u[1] = c1; f.u[2] = c2; f.u[3] = c3;
                pa[nb * 2 + h2] = f.v;
            }
        }

        // PV: accO[db] += P . V (B-frags from swizzled VT)
        __builtin_amdgcn_s_setprio(1);
#pragma unroll
        for (int db = 0; db < 2; ++db)
#pragma unroll
            for (int ks = 0; ks < 4; ++ks) {
                bf16x8 vf = *(const bf16x8*)&bV[(db * 32 + l31) * 64 + ((ks * 16 + hi * 8) ^ swz)];
                accO[db] = __builtin_amdgcn_mfma_f32_32x32x16_bf16(pa[ks], vf, accO[db], 0, 0, 0);
            }
        __builtin_amdgcn_s_setprio(0);

        __syncthreads();   // all reads of buf[cur] done; next iter overwrites it
    }

    // combine L halves (lane <-> lane+32 hold complementary kv columns of q=l31)
    unsigned lu = __float_as_uint(Lp), lv = lu;
    plane32swap(lu, lv);
    const float Ltot = __uint_as_float(lu) + __uint_as_float(lv);
    if (hi == 0) sL[w][l31] = Ltot;
    __syncthreads();

    const int b = bh >> 4, h = bh & 15;
    const int qg0 = qt * 128 + w * 32;
#pragma unroll
    for (int r = 0; r < 16; ++r) {
        const int ql = (r & 3) + 8 * (r >> 2) + 4 * hi;   // C-row -> q within warp
        const float inv = 1.0f / sL[w][ql];
        const int row = qg0 + ql;
#pragma unroll
        for (int db = 0; db < 2; ++db)
            O[((long)b * SEQ + row) * DMODEL + h * HD + db * 32 + l31] = accO[db][r] * inv;
    }
}

extern "C" void kernel_launch(void* const* d_in, const int* in_sizes, int n_in,
                              void* d_out, int out_size, void* d_ws, size_t ws_size,
                              hipStream_t stream) {
    const float* x  = (const float*)d_in[0];   // (2, 2048, 1024) fp32
    const float* Wq = (const float*)d_in[1];   // (3072, 1024) fp32
    float* out = (float*)d_out;                // (2, 2048, 1024) fp32

    const int NX = BATCH * SEQ * DMODEL;        // 4194304
    const int NW = 3 * DMODEL * DMODEL;         // 3145728
    const int NQKV = BATCH * NHEADS * SEQ * HD; // 4194304

    ushort* xb = (ushort*)d_ws;
    ushort* wb = xb + NX;
    ushort* q  = wb + NW;
    ushort* k  = q + NQKV;
    ushort* vtmp = k + NQKV;
    ushort* vt = xb;    // xb is dead after the GEMM; alias it for V^T (same size)

    cvt2<<<(NX + NW) / 4 / 256, 256, 0, stream>>>(x, xb, NX, Wq, wb, NW);

    dim3 g1(4096 / 128, 3072 / 128);   // 32 x 24
    qkv_gemm<<<g1, 256, 0, stream>>>(xb, wb, q, k, vtmp);

    dim3 gt(SEQ / 64, BATCH * NHEADS); // 32 x 32
    tr_v<<<gt, 256, 0, stream>>>(vtmp, vt);

    dim3 g2(SEQ / 128, BATCH * NHEADS); // 16 x 32
    attn_kernel<<<g2, 256, 0, stream>>>(q, k, vt, out);
}

// Round 3
// 177.658 us; speedup vs baseline: 1.0955x; 1.0044x over previous
//
#include <hip/hip_runtime.h>
#include <hip/hip_bf16.h>

#define SEQ 2048
#define DMODEL 1024
#define NHEADS 16
#define HD 64
#define BATCH 2

typedef short bf16x8 __attribute__((ext_vector_type(8)));
typedef float f32x4 __attribute__((ext_vector_type(4)));
typedef float f32x16 __attribute__((ext_vector_type(16)));

// fp32 -> bf16 (RNE), finite inputs only
static __device__ inline ushort f2bf(float f) {
    unsigned u = __float_as_uint(f);
    return (ushort)((u + 0x7fffu + ((u >> 16) & 1u)) >> 16);
}

// packed pair convert: low 16 = a, high 16 = b (v_cvt_pk_bf16_f32 on gfx950)
static __device__ inline unsigned pk2bf(float a, float b) {
    __hip_bfloat162 h = __float22bfloat162_rn(make_float2(a, b));
    union { __hip_bfloat162 h; unsigned u; } c; c.h = h;
    return c.u;
}

static __device__ inline void async16(const ushort* g, ushort* l) {
    __builtin_amdgcn_global_load_lds((const __attribute__((address_space(1))) void*)g,
                                     (__attribute__((address_space(3))) void*)l, 16, 0, 0);
}

// exchange dst-hi-lanes with src-lo-lanes (v_permlane32_swap_b32)
static __device__ inline void plane32swap(unsigned& a, unsigned& b) {
    asm volatile("v_permlane32_swap_b32 %0, %1" : "+v"(a), "+v"(b));
}

// one launch: convert x and W_qkv fp32 -> bf16
__global__ void cvt2(const float* __restrict__ a, ushort* __restrict__ da, int na,
                     const float* __restrict__ b, ushort* __restrict__ db, int nb) {
    long i = (long)(blockIdx.x * blockDim.x + threadIdx.x) * 4;
    const float* s; ushort* d;
    if (i < na) { s = a + i; d = da + i; }
    else { long j = i - na; if (j >= nb) return; s = b + j; d = db + j; }
    float4 v = *(const float4*)s;
    ushort4 o; o.x = f2bf(v.x); o.y = f2bf(v.y); o.z = f2bf(v.z); o.w = f2bf(v.w);
    *(ushort4*)d = o;
}

// LDS: staging (2x16KB) and epilogue C-tile (32KB) share the same 32KB block
union GemmSmem {
    struct { ushort A[128 * 64]; ushort B[128 * 64]; } st;
    ushort C[128 * 128];   // bf16 C-tile, XOR-swizzled: phys_col = col ^ (8*(row&7))
};

// qkv = x @ W^T. m97 K-loop (unpadded LDS, global_load_lds w=16).
__global__ __launch_bounds__(256) void qkv_gemm(
        const ushort* __restrict__ X, const ushort* __restrict__ W,
        ushort* __restrict__ Qd, ushort* __restrict__ Kd, ushort* __restrict__ Vd) {
    __shared__ GemmSmem sm;
    const int t = threadIdx.x;
    const int lane = t & 63, l15 = lane & 15, quad = lane >> 4;
    const int w = t >> 6, wm = w >> 1, wn = w & 1;
    const int gm = blockIdx.x, gn = blockIdx.y;
    const int srow = t >> 3, scol = (t & 7) * 8;

    f32x4 acc[4][4] = {};

    for (int kt = 0; kt < 16; ++kt) {
        const int k0 = kt * 64;
        __syncthreads();
#pragma unroll
        for (int inst = 0; inst < 4; ++inst) {
            async16(&X[(gm * 128 + inst * 32 + srow) * 1024 + k0 + scol], &sm.st.A[inst * 2048 + t * 8]);
            async16(&W[(gn * 128 + inst * 32 + srow) * 1024 + k0 + scol], &sm.st.B[inst * 2048 + t * 8]);
        }
        __syncthreads();
#pragma unroll
        for (int ks = 0; ks < 2; ++ks) {
            const int kk = ks * 32 + quad * 8;
            bf16x8 af[4], bfr[4];
#pragma unroll
            for (int i = 0; i < 4; ++i) {
                af[i]  = *(const bf16x8*)&sm.st.A[(wm * 64 + i * 16 + l15) * 64 + kk];
                bfr[i] = *(const bf16x8*)&sm.st.B[(wn * 64 + i * 16 + l15) * 64 + kk];
            }
#pragma unroll
            for (int i = 0; i < 4; ++i)
#pragma unroll
                for (int j = 0; j < 4; ++j)
                    acc[i][j] = __builtin_amdgcn_mfma_f32_16x16x32_bf16(af[i], bfr[j], acc[i][j], 0, 0, 0);
        }
    }

    __syncthreads();   // all frag reads done; reuse LDS as C-tile
    const float sc = (gn < 8) ? (0.125f * 1.44269504f) : 1.0f;  // fold softmax scale into Q
#pragma unroll
    for (int i = 0; i < 4; ++i)
#pragma unroll
        for (int reg = 0; reg < 4; ++reg) {
            const int row = wm * 64 + i * 16 + quad * 4 + reg;
            const int sw = (row & 7) * 8;
#pragma unroll
            for (int jp = 0; jp < 4; jp += 2) {
                unsigned u = pk2bf(acc[i][jp][reg] * sc, acc[i][jp + 1][reg] * sc);
                sm.C[row * 128 + ((wn * 64 + jp * 16 + l15) ^ sw)] = (ushort)u;
                sm.C[row * 128 + ((wn * 64 + (jp + 1) * 16 + l15) ^ sw)] = (ushort)(u >> 16);
            }
        }
    __syncthreads();

    const int which = gn >> 3;   // 0=Q 1=K 2=V (uniform per block)
    ushort* dst = (which == 0) ? Qd : ((which == 1) ? Kd : Vd);
    const int rloc = t >> 4, l = t & 15;
#pragma unroll
    for (int pass = 0; pass < 8; ++pass) {
        const int r = pass * 16 + rloc;
        bf16x8 v = *(const bf16x8*)&sm.C[r * 128 + ((l * 8) ^ ((r & 7) * 8))];
        const int ng = gm * 128 + r;
        const int b = ng >> 11, n = ng & 2047;
        const int cl = (gn * 128 + l * 8) & 1023;
        const int h = cl >> 6, hd = cl & 63;
        *(bf16x8*)&dst[(((b * NHEADS + h) * SEQ) + n) * HD + hd] = v;
    }
}

// V [bh][n][hd] -> VT [bh][hd][n], LDS-tiled 64x64
__global__ __launch_bounds__(256) void tr_v(const ushort* __restrict__ src, ushort* __restrict__ dst) {
    __shared__ ushort sT[64][72];
    const int t = threadIdx.x;
    const int bh = blockIdx.y, nt = blockIdx.x;
    const int r0 = t >> 3, c8 = (t & 7) * 8;
    const ushort* sp = src + ((long)bh * SEQ + nt * 64) * HD;
#pragma unroll
    for (int rr = 0; rr < 64; rr += 32)
        *(bf16x8*)&sT[rr + r0][c8] = *(const bf16x8*)&sp[(rr + r0) * HD + c8];
    __syncthreads();
    ushort* dp = dst + (long)bh * HD * SEQ + nt * 64;
#pragma unroll
    for (int rr = 0; rr < 64; rr += 32) {
        const int hd = rr + r0;
        bf16x8 v;
#pragma unroll
        for (int j = 0; j < 8; ++j) v[j] = (short)sT[c8 + j][hd];
        *(bf16x8*)&dp[(long)hd * SEQ + c8] = v;
    }
}

// Flash attention (no-max softmax; logits bounded, scale folded into Q).
// 4 warps x 32 q-rows = 128 q/block; KVBLK=128 per barrier-iter, split into
// A/B 64-kv halves with interleaved phases (QK-A, QK-B, SM-A, PV-A, SM-B,
// PV-B) so one half's softmax VALU overlaps the other half's MFMA execution
// inside the same wave. Swapped QK^T (32x32x16) keeps the P-row in-lane;
// P->A-frag via cvt_pk + v_permlane32_swap. K/VT double-buffered in LDS via
// global_load_lds, XOR-swizzled through a pre-swizzled global source.
// 2 independent 4-warp workgroups per CU (separate barrier domains).
__global__ __launch_bounds__(256, 2) void attn_kernel(
        const ushort* __restrict__ Q, const ushort* __restrict__ K,
        const ushort* __restrict__ VT, float* __restrict__ O) {
    __shared__ ushort sK[2][128 * 64];   // [kv][d]: 128 rows x 128B, swz 16B slots
    __shared__ ushort sVT[2][64 * 128];  // [d][kv]: 64 rows x 256B, swz 16B slots
    __shared__ float sL[4][32];

    const int t = threadIdx.x;
    const int lane = t & 63, l31 = lane & 31, hi = lane >> 5;
    const int w = t >> 6;

    // XCD swizzle: blocks dispatch round-robin by flat id % 8. Map so all 16
    // q-blocks of one bh share an XCD; each XCD caches 4 bh of K/V (2MB) in L2.
    const int flat = blockIdx.y * gridDim.x + blockIdx.x;   // 0..511
    const int qt = (flat >> 3) & 15;
    const int bh = (flat & 7) + ((flat >> 7) << 3);

    const ushort* Qp = Q + ((long)bh * SEQ + qt * 128 + w * 32) * HD;
    const ushort* Kp = K + (long)bh * SEQ * HD;
    const ushort* Vp = VT + (long)bh * HD * SEQ;

    // Q fragments (B operand): lane holds Q[q=l31][k = ks*16 + hi*8 + j]
    bf16x8 bq[4];
#pragma unroll
    for (int ks = 0; ks < 4; ++ks)
        bq[ks] = *(const bf16x8*)&Qp[l31 * HD + ks * 16 + hi * 8];

    // K staging: chunk c covers rows c*32 + (t>>3); 16B slot t&7 of a 128B row;
    // linear LDS dest, swizzle via pre-swizzled SOURCE column.
    const int krow = t >> 3;                          // 0..31
    const int kcol = ((t & 7) ^ (krow & 7)) * 8;
    const ushort* gK = Kp + krow * HD + kcol;
    // V staging: chunk c covers d-rows c*16 + (t>>4); 16B slot t&15 of a 256B row.
    const int vrow = t >> 4;                          // 0..15
    const int vcol = ((t & 15) ^ (vrow & 7)) * 8;
    const ushort* gV = Vp + (long)vrow * SEQ + vcol;

    ushort* lK[2] = { &sK[0][t * 8], &sK[1][t * 8] };
    ushort* lV[2] = { &sVT[0][t * 8], &sVT[1][t * 8] };

    f32x16 accO[2] = {};
    f32x4 Lp4 = {};
    const int swz = (l31 & 7) << 3;

    // prologue: stage tile 0 (syncthreads drains vmcnt)
#pragma unroll
    for (int c = 0; c < 4; ++c) {
        async16(gK + c * 32 * HD, lK[0] + c * 2048);
        async16(gV + (long)c * 16 * SEQ, lV[0] + c * 2048);
    }
    __syncthreads();

    for (int kt = 0; kt < 16; ++kt) {
        const int cur = kt & 1;
        if (kt < 15) {      // prefetch next 128-kv tile into the other buffer
            const ushort* nK = gK + (kt + 1) * 128 * HD;
            const ushort* nV = gV + (kt + 1) * 128;
#pragma unroll
            for (int c = 0; c < 4; ++c) {
                async16(nK + c * 32 * HD, lK[cur ^ 1] + c * 2048);
                async16(nV + (long)c * 16 * SEQ, lV[cur ^ 1] + c * 2048);
            }
        }
        const ushort* bK = sK[cur];
        const ushort* bV = sVT[cur];

        // QK^T swapped, all 4 32-kv blocks: s[nb] = K-block(nb) . Q^T
        f32x16 s[4];
        __builtin_amdgcn_s_setprio(1);
#pragma unroll
        for (int nb = 0; nb < 4; ++nb) {
            f32x16 z = {};
#pragma unroll
            for (int ks = 0; ks < 4; ++ks) {
                bf16x8 ak = *(const bf16x8*)&bK[(nb * 32 + l31) * 64 + ((ks * 16 + hi * 8) ^ swz)];
                z = __builtin_amdgcn_mfma_f32_32x32x16_bf16(ak, bq[ks], z, 0, 0, 0);
            }
            s[nb] = z;
        }
        __builtin_amdgcn_s_setprio(0);

        // two 64-kv halves: SM(h) runs while the previous MFMA cluster drains;
        // PV(h) issues before SM of the next half.
#pragma unroll
        for (int h = 0; h < 2; ++h) {
            bf16x8 pa[4];
#pragma unroll
            for (int nb = 0; nb < 2; ++nb) {
                float p[16];
#pragma unroll
                for (int r = 0; r < 16; ++r) p[r] = exp2f(s[h * 2 + nb][r]);
#pragma unroll
                for (int r = 0; r < 16; ++r) Lp4[r & 3] += p[r];
#pragma unroll
                for (int h2 = 0; h2 < 2; ++h2) {
                    const int b = 8 * h2;
                    unsigned c0 = pk2bf(p[b + 0], p[b + 1]);
                    unsigned c1 = pk2bf(p[b + 2], p[b + 3]);
                    unsigned c2 = pk2bf(p[b + 4], p[b + 5]);
                    unsigned c3 = pk2bf(p[b + 6], p[b + 7]);
                    plane32swap(c0, c2);
                    plane32swap(c1, c3);
                    union { unsigned u[4]; bf16x8 v; } f;
                    f.u[0] = c0; f.u[1] = c1; f.u[2] = c2; f.u[3] = c3;
                    pa[nb * 2 + h2] = f.v;
                }
            }
            // PV half h: accO[db] += P(:, h*64..h*64+63) . V-half
            __builtin_amdgcn_s_setprio(1);
#pragma unroll
            for (int db = 0; db < 2; ++db)
#pragma unroll
                for (int ks = 0; ks < 4; ++ks) {
                    bf16x8 vf = *(const bf16x8*)&bV[(db * 32 + l31) * 128 + h * 64 + ((ks * 16 + hi * 8) ^ swz)];
                    accO[db] = __builtin_amdgcn_mfma_f32_32x32x16_bf16(pa[ks], vf, accO[db], 0, 0, 0);
                }
            __builtin_amdgcn_s_setprio(0);
        }

        __syncthreads();   // all reads of buf[cur] done; next iter overwrites it
    }

    // combine L: 4 ILP partials, then lane <-> lane+32 halves
    const float Lp = (Lp4[0] + Lp4[1]) + (Lp4[2] + Lp4[3]);
    unsigned lu = __float_as_uint(Lp), lv = lu;
    plane32swap(lu, lv);
    const float Ltot = __uint_as_float(lu) + __uint_as_float(lv);
    if (hi == 0) sL[w][l31] = Ltot;
    __syncthreads();

    const int b = bh >> 4, h = bh & 15;
    const int qg0 = qt * 128 + w * 32;
#pragma unroll
    for (int r = 0; r < 16; ++r) {
        const int ql = (r & 3) + 8 * (r >> 2) + 4 * hi;   // C-row -> q within warp
        const float inv = 1.0f / sL[w][ql];
        const int row = qg0 + ql;
#pragma unroll
        for (int db = 0; db < 2; ++db)
            O[((long)b * SEQ + row) * DMODEL + h * HD + db * 32 + l31] = accO[db][r] * inv;
    }
}

extern "C" void kernel_launch(void* const* d_in, const int* in_sizes, int n_in,
                              void* d_out, int out_size, void* d_ws, size_t ws_size,
                              hipStream_t stream) {
    const float* x  = (const float*)d_in[0];   // (2, 2048, 1024) fp32
    const float* Wq = (const float*)d_in[1];   // (3072, 1024) fp32
    float* out = (float*)d_out;                // (2, 2048, 1024) fp32

    const int NX = BATCH * SEQ * DMODEL;        // 4194304
    const int NW = 3 * DMODEL * DMODEL;         // 3145728
    const int NQKV = BATCH * NHEADS * SEQ * HD; // 4194304

    ushort* xb = (ushort*)d_ws;
    ushort* wb = xb + NX;
    ushort* q  = wb + NW;
    ushort* k  = q + NQKV;
    ushort* vtmp = k + NQKV;
    ushort* vt = xb;    // xb is dead after the GEMM; alias it for V^T (same size)

    cvt2<<<(NX + NW) / 4 / 256, 256, 0, stream>>>(x, xb, NX, Wq, wb, NW);

    dim3 g1(4096 / 128, 3072 / 128);   // 32 x 24
    qkv_gemm<<<g1, 256, 0, stream>>>(xb, wb, q, k, vtmp);

    dim3 gt(SEQ / 64, BATCH * NHEADS); // 32 x 32
    tr_v<<<gt, 256, 0, stream>>>(vtmp, vt);

    dim3 g2(SEQ / 128, BATCH * NHEADS); // 16 x 32
    attn_kernel<<<g2, 256, 0, stream>>>(q, k, vt, out);
}

// Round 4
// 170.083 us; speedup vs baseline: 1.1443x; 1.0445x over previous
//
#include <hip/hip_runtime.h>
#include <hip/hip_bf16.h>

#define SEQ 2048
#define DMODEL 1024
#define NHEADS 16
#define HD 64
#define BATCH 2

typedef short bf16x8 __attribute__((ext_vector_type(8)));
typedef float f32x4 __attribute__((ext_vector_type(4)));
typedef float f32x16 __attribute__((ext_vector_type(16)));

// fp32 -> bf16 (RNE), finite inputs only
static __device__ inline ushort f2bf(float f) {
    unsigned u = __float_as_uint(f);
    return (ushort)((u + 0x7fffu + ((u >> 16) & 1u)) >> 16);
}

// packed pair convert: low 16 = a, high 16 = b (v_cvt_pk_bf16_f32 on gfx950)
static __device__ inline unsigned pk2bf(float a, float b) {
    __hip_bfloat162 h = __float22bfloat162_rn(make_float2(a, b));
    union { __hip_bfloat162 h; unsigned u; } c; c.h = h;
    return c.u;
}

static __device__ inline void async16(const ushort* g, ushort* l) {
    __builtin_amdgcn_global_load_lds((const __attribute__((address_space(1))) void*)g,
                                     (__attribute__((address_space(3))) void*)l, 16, 0, 0);
}

// exchange dst-hi-lanes with src-lo-lanes (v_permlane32_swap_b32)
static __device__ inline void plane32swap(unsigned& a, unsigned& b) {
    asm volatile("v_permlane32_swap_b32 %0, %1" : "+v"(a), "+v"(b));
}

// one launch: convert x and W_qkv fp32 -> bf16
__global__ void cvt2(const float* __restrict__ a, ushort* __restrict__ da, int na,
                     const float* __restrict__ b, ushort* __restrict__ db, int nb) {
    long i = (long)(blockIdx.x * blockDim.x + threadIdx.x) * 4;
    const float* s; ushort* d;
    if (i < na) { s = a + i; d = da + i; }
    else { long j = i - na; if (j >= nb) return; s = b + j; d = db + j; }
    float4 v = *(const float4*)s;
    ushort4 o; o.x = f2bf(v.x); o.y = f2bf(v.y); o.z = f2bf(v.z); o.w = f2bf(v.w);
    *(ushort4*)d = o;
}

// LDS: staging (2x16KB) and epilogue C-tile (32KB) share the same 32KB block
union GemmSmem {
    struct { ushort A[128 * 64]; ushort B[128 * 64]; } st;
    ushort C[128 * 128];   // bf16 C-tile, XOR-swizzled: phys_col = col ^ (8*(row&7))
};

// qkv = x @ W^T. m97 K-loop (unpadded LDS, global_load_lds w=16).
__global__ __launch_bounds__(256) void qkv_gemm(
        const ushort* __restrict__ X, const ushort* __restrict__ W,
        ushort* __restrict__ Qd, ushort* __restrict__ Kd, ushort* __restrict__ Vd) {
    __shared__ GemmSmem sm;
    const int t = threadIdx.x;
    const int lane = t & 63, l15 = lane & 15, quad = lane >> 4;
    const int w = t >> 6, wm = w >> 1, wn = w & 1;
    const int gm = blockIdx.x, gn = blockIdx.y;
    const int srow = t >> 3, scol = (t & 7) * 8;

    f32x4 acc[4][4] = {};

    for (int kt = 0; kt < 16; ++kt) {
        const int k0 = kt * 64;
        __syncthreads();
#pragma unroll
        for (int inst = 0; inst < 4; ++inst) {
            async16(&X[(gm * 128 + inst * 32 + srow) * 1024 + k0 + scol], &sm.st.A[inst * 2048 + t * 8]);
            async16(&W[(gn * 128 + inst * 32 + srow) * 1024 + k0 + scol], &sm.st.B[inst * 2048 + t * 8]);
        }
        __syncthreads();
#pragma unroll
        for (int ks = 0; ks < 2; ++ks) {
            const int kk = ks * 32 + quad * 8;
            bf16x8 af[4], bfr[4];
#pragma unroll
            for (int i = 0; i < 4; ++i) {
                af[i]  = *(const bf16x8*)&sm.st.A[(wm * 64 + i * 16 + l15) * 64 + kk];
                bfr[i] = *(const bf16x8*)&sm.st.B[(wn * 64 + i * 16 + l15) * 64 + kk];
            }
#pragma unroll
            for (int i = 0; i < 4; ++i)
#pragma unroll
                for (int j = 0; j < 4; ++j)
                    acc[i][j] = __builtin_amdgcn_mfma_f32_16x16x32_bf16(af[i], bfr[j], acc[i][j], 0, 0, 0);
        }
    }

    __syncthreads();   // all frag reads done; reuse LDS as C-tile
    const float sc = (gn < 8) ? (0.125f * 1.44269504f) : 1.0f;  // fold softmax scale into Q
#pragma unroll
    for (int i = 0; i < 4; ++i)
#pragma unroll
        for (int reg = 0; reg < 4; ++reg) {
            const int row = wm * 64 + i * 16 + quad * 4 + reg;
            const int sw = (row & 7) * 8;
#pragma unroll
            for (int jp = 0; jp < 4; jp += 2) {
                unsigned u = pk2bf(acc[i][jp][reg] * sc, acc[i][jp + 1][reg] * sc);
                sm.C[row * 128 + ((wn * 64 + jp * 16 + l15) ^ sw)] = (ushort)u;
                sm.C[row * 128 + ((wn * 64 + (jp + 1) * 16 + l15) ^ sw)] = (ushort)(u >> 16);
            }
        }
    __syncthreads();

    const int which = gn >> 3;   // 0=Q 1=K 2=V (uniform per block)
    ushort* dst = (which == 0) ? Qd : ((which == 1) ? Kd : Vd);
    const int rloc = t >> 4, l = t & 15;
#pragma unroll
    for (int pass = 0; pass < 8; ++pass) {
        const int r = pass * 16 + rloc;
        bf16x8 v = *(const bf16x8*)&sm.C[r * 128 + ((l * 8) ^ ((r & 7) * 8))];
        const int ng = gm * 128 + r;
        const int b = ng >> 11, n = ng & 2047;
        const int cl = (gn * 128 + l * 8) & 1023;
        const int h = cl >> 6, hd = cl & 63;
        *(bf16x8*)&dst[(((b * NHEADS + h) * SEQ) + n) * HD + hd] = v;
    }
}

// V [bh][n][hd] -> VT [bh][hd][n], LDS-tiled 64x64
__global__ __launch_bounds__(256) void tr_v(const ushort* __restrict__ src, ushort* __restrict__ dst) {
    __shared__ ushort sT[64][72];
    const int t = threadIdx.x;
    const int bh = blockIdx.y, nt = blockIdx.x;
    const int r0 = t >> 3, c8 = (t & 7) * 8;
    const ushort* sp = src + ((long)bh * SEQ + nt * 64) * HD;
#pragma unroll
    for (int rr = 0; rr < 64; rr += 32)
        *(bf16x8*)&sT[rr + r0][c8] = *(const bf16x8*)&sp[(rr + r0) * HD + c8];
    __syncthreads();
    ushort* dp = dst + (long)bh * HD * SEQ + nt * 64;
#pragma unroll
    for (int rr = 0; rr < 64; rr += 32) {
        const int hd = rr + r0;
        bf16x8 v;
#pragma unroll
        for (int j = 0; j < 8; ++j) v[j] = (short)sT[c8 + j][hd];
        *(bf16x8*)&dp[(long)hd * SEQ + c8] = v;
    }
}

// Flash attention (no-max softmax; logits bounded, scale folded into Q).
// 4 waves x 64 q-rows = 256 q/block; KVBLK=128/iter. Each K-frag and V-frag
// ds_read feeds TWO MFMAs (two q-half B/A operands, register-resident) ->
// 64 FLOP per LDS byte (2x the 32-q version), LDS reads per MFMA halved.
// Grid 256 = 1 block/CU, 1 wave/SIMD: all hiding from ILP; launch_bounds(256,1)
// gives the 512-reg budget so s[8] (128 VGPR) + 4 accO (64) fit without spill.
// Swapped QK^T (32x32x16) keeps P-rows in-lane; softmax in-register via raw
// v_exp_f32; P->A-frag via cvt_pk + v_permlane32_swap. K/VT double-buffered
// via global_load_lds, XOR-swizzled through a pre-swizzled global source.
__global__ __launch_bounds__(256, 1) void attn_kernel(
        const ushort* __restrict__ Q, const ushort* __restrict__ K,
        const ushort* __restrict__ VT, float* __restrict__ O) {
    __shared__ ushort sK[2][128 * 64];   // [kv][d]: 128 rows x 128B, swz 16B slots
    __shared__ ushort sVT[2][64 * 128];  // [d][kv]: 64 rows x 256B, swz 16B slots
    __shared__ float sL[4][64];

    const int t = threadIdx.x;
    const int lane = t & 63, l31 = lane & 31, hi = lane >> 5;
    const int w = t >> 6;

    // XCD swizzle: blocks dispatch round-robin by flat id % 8. All 8 q-blocks
    // of one bh share an XCD; each XCD caches 4 bh of K/V (2MB) in its L2.
    // flat bits: [2:0]=bh-low, [5:3]=qt, [7:6]=bh-high (bijective over 256).
    const int flat = blockIdx.y * gridDim.x + blockIdx.x;   // 0..255
    const int qt = (flat >> 3) & 7;
    const int bh = (flat & 7) + ((flat >> 6) << 3);

    const ushort* Qp = Q + ((long)bh * SEQ + qt * 256 + w * 64) * HD;
    const ushort* Kp = K + (long)bh * SEQ * HD;
    const ushort* Vp = VT + (long)bh * HD * SEQ;

    // Q fragments, two q-halves (B operand): lane holds Q[q][k=ks*16+hi*8+j]
    bf16x8 bq[2][4];
#pragma unroll
    for (int qh = 0; qh < 2; ++qh)
#pragma unroll
        for (int ks = 0; ks < 4; ++ks)
            bq[qh][ks] = *(const bf16x8*)&Qp[(qh * 32 + l31) * HD + ks * 16 + hi * 8];

    // K staging: chunk c covers rows c*32 + (t>>3); 16B slot t&7 of a 128B row;
    // linear LDS dest, swizzle via pre-swizzled SOURCE column.
    const int krow = t >> 3;                          // 0..31
    const int kcol = ((t & 7) ^ (krow & 7)) * 8;
    const ushort* gK = Kp + krow * HD + kcol;
    // V staging: chunk c covers d-rows c*16 + (t>>4); 16B slot t&15 of a 256B row.
    const int vrow = t >> 4;                          // 0..15
    const int vcol = ((t & 15) ^ (vrow & 7)) * 8;
    const ushort* gV = Vp + (long)vrow * SEQ + vcol;

    ushort* lK[2] = { &sK[0][t * 8], &sK[1][t * 8] };
    ushort* lV[2] = { &sVT[0][t * 8], &sVT[1][t * 8] };

    f32x16 accA[2] = {}, accB[2] = {};
    f32x4 LpA = {}, LpB = {};
    const int swz = (l31 & 7) << 3;

    // prologue: stage tile 0 (syncthreads drains vmcnt)
#pragma unroll
    for (int c = 0; c < 4; ++c) {
        async16(gK + c * 32 * HD, lK[0] + c * 2048);
        async16(gV + (long)c * 16 * SEQ, lV[0] + c * 2048);
    }
    __syncthreads();

    for (int kt = 0; kt < 16; ++kt) {
        const int cur = kt & 1;
        if (kt < 15) {      // prefetch next 128-kv tile into the other buffer
            const ushort* nK = gK + (kt + 1) * 128 * HD;
            const ushort* nV = gV + (kt + 1) * 128;
#pragma unroll
            for (int c = 0; c < 4; ++c) {
                async16(nK + c * 32 * HD, lK[cur ^ 1] + c * 2048);
                async16(nV + (long)c * 16 * SEQ, lV[cur ^ 1] + c * 2048);
            }
        }
        const ushort* bK = sK[cur];
        const ushort* bV = sVT[cur];

        // QK^T swapped, both q-halves share every K-frag read:
        // sA[nb]/sB[nb] = K-block(nb) . Qhalf^T ; lane holds P-row q=l31
        f32x16 sA[4], sB[4];
#pragma unroll
        for (int nb = 0; nb < 4; ++nb) {
            f32x16 zA = {}, zB = {};
#pragma unroll
            for (int ks = 0; ks < 4; ++ks) {
                bf16x8 ak = *(const bf16x8*)&bK[(nb * 32 + l31) * 64 + ((ks * 16 + hi * 8) ^ swz)];
                zA = __builtin_amdgcn_mfma_f32_32x32x16_bf16(ak, bq[0][ks], zA, 0, 0, 0);
                zB = __builtin_amdgcn_mfma_f32_32x32x16_bf16(ak, bq[1][ks], zB, 0, 0, 0);
            }
            sA[nb] = zA; sB[nb] = zB;
        }

        // two 64-kv halves: softmax (VALU) of one interleaves with PV MFMAs
#pragma unroll
        for (int h = 0; h < 2; ++h) {
            bf16x8 paA[4], paB[4];
#pragma unroll
            for (int nb2 = 0; nb2 < 2; ++nb2) {
                float pA[16], pB[16];
#pragma unroll
                for (int r = 0; r < 16; ++r) {
                    pA[r] = __builtin_amdgcn_exp2f(sA[h * 2 + nb2][r]);
                    pB[r] = __builtin_amdgcn_exp2f(sB[h * 2 + nb2][r]);
                }
#pragma unroll
                for (int r = 0; r < 16; ++r) { LpA[r & 3] += pA[r]; LpB[r & 3] += pB[r]; }
#pragma unroll
                for (int h2 = 0; h2 < 2; ++h2) {
                    const int b = 8 * h2;
                    unsigned a0 = pk2bf(pA[b + 0], pA[b + 1]);
                    unsigned a1 = pk2bf(pA[b + 2], pA[b + 3]);
                    unsigned a2 = pk2bf(pA[b + 4], pA[b + 5]);
                    unsigned a3 = pk2bf(pA[b + 6], pA[b + 7]);
                    plane32swap(a0, a2);
                    plane32swap(a1, a3);
                    union { unsigned u[4]; bf16x8 v; } fa;
                    fa.u[0] = a0; fa.u[1] = a1; fa.u[2] = a2; fa.u[3] = a3;
                    paA[nb2 * 2 + h2] = fa.v;
                    unsigned b0 = pk2bf(pB[b + 0], pB[b + 1]);
                    unsigned b1 = pk2bf(pB[b + 2], pB[b + 3]);
                    unsigned b2 = pk2bf(pB[b + 4], pB[b + 5]);
                    unsigned b3 = pk2bf(pB[b + 6], pB[b + 7]);
                    plane32swap(b0, b2);
                    plane32swap(b1, b3);
                    union { unsigned u[4]; bf16x8 v; } fb;
                    fb.u[0] = b0; fb.u[1] = b1; fb.u[2] = b2; fb.u[3] = b3;
                    paB[nb2 * 2 + h2] = fb.v;
                }
            }
            // PV half h: both q-halves share every V-frag read
#pragma unroll
            for (int db = 0; db < 2; ++db)
#pragma unroll
                for (int ks = 0; ks < 4; ++ks) {
                    bf16x8 vf = *(const bf16x8*)&bV[(db * 32 + l31) * 128 + h * 64 + ((ks * 16 + hi * 8) ^ swz)];
                    accA[db] = __builtin_amdgcn_mfma_f32_32x32x16_bf16(paA[ks], vf, accA[db], 0, 0, 0);
                    accB[db] = __builtin_amdgcn_mfma_f32_32x32x16_bf16(paB[ks], vf, accB[db], 0, 0, 0);
                }
        }

        __syncthreads();   // all reads of buf[cur] done; next iter overwrites it
    }

    // combine L: 4 ILP partials, then lane <-> lane+32 halves; all lanes end
    // with the total for q=l31 of their q-half.
    {
        const float la = (LpA[0] + LpA[1]) + (LpA[2] + LpA[3]);
        unsigned lu = __float_as_uint(la), lv = lu;
        plane32swap(lu, lv);
        const float lb = (LpB[0] + LpB[1]) + (LpB[2] + LpB[3]);
        unsigned mu = __float_as_uint(lb), mv = mu;
        plane32swap(mu, mv);
        if (hi == 0) {
            sL[w][l31]      = __uint_as_float(lu) + __uint_as_float(lv);
            sL[w][32 + l31] = __uint_as_float(mu) + __uint_as_float(mv);
        }
    }
    __syncthreads();

    const int b = bh >> 4, h = bh & 15;
    const int qg0 = qt * 256 + w * 64;
#pragma unroll
    for (int r = 0; r < 16; ++r) {
        const int ql = (r & 3) + 8 * (r >> 2) + 4 * hi;   // C-row -> q within 32
        const float invA = 1.0f / sL[w][ql];
        const float invB = 1.0f / sL[w][32 + ql];
#pragma unroll
        for (int db = 0; db < 2; ++db) {
            O[((long)b * SEQ + qg0 + ql) * DMODEL + h * HD + db * 32 + l31]      = accA[db][r] * invA;
            O[((long)b * SEQ + qg0 + 32 + ql) * DMODEL + h * HD + db * 32 + l31] = accB[db][r] * invB;
        }
    }
}

extern "C" void kernel_launch(void* const* d_in, const int* in_sizes, int n_in,
                              void* d_out, int out_size, void* d_ws, size_t ws_size,
                              hipStream_t stream) {
    const float* x  = (const float*)d_in[0];   // (2, 2048, 1024) fp32
    const float* Wq = (const float*)d_in[1];   // (3072, 1024) fp32
    float* out = (float*)d_out;                // (2, 2048, 1024) fp32

    const int NX = BATCH * SEQ * DMODEL;        // 4194304
    const int NW = 3 * DMODEL * DMODEL;         // 3145728
    const int NQKV = BATCH * NHEADS * SEQ * HD; // 4194304

    ushort* xb = (ushort*)d_ws;
    ushort* wb = xb + NX;
    ushort* q  = wb + NW;
    ushort* k  = q + NQKV;
    ushort* vtmp = k + NQKV;
    ushort* vt = xb;    // xb is dead after the GEMM; alias it for V^T (same size)

    cvt2<<<(NX + NW) / 4 / 256, 256, 0, stream>>>(x, xb, NX, Wq, wb, NW);

    dim3 g1(4096 / 128, 3072 / 128);   // 32 x 24
    qkv_gemm<<<g1, 256, 0, stream>>>(xb, wb, q, k, vtmp);

    dim3 gt(SEQ / 64, BATCH * NHEADS); // 32 x 32
    tr_v<<<gt, 256, 0, stream>>>(vtmp, vt);

    dim3 g2(SEQ / 256, BATCH * NHEADS); // 8 x 32
    attn_kernel<<<g2, 256, 0, stream>>>(q, k, vt, out);
}

// Round 5
// 165.815 us; speedup vs baseline: 1.1737x; 1.0257x over previous
//
#include <hip/hip_runtime.h>
#include <hip/hip_bf16.h>

#define SEQ 2048
#define DMODEL 1024
#define NHEADS 16
#define HD 64
#define BATCH 2

typedef short bf16x8 __attribute__((ext_vector_type(8)));
typedef float f32x4 __attribute__((ext_vector_type(4)));
typedef float f32x16 __attribute__((ext_vector_type(16)));

// fp32 -> bf16 (RNE), finite inputs only
static __device__ inline ushort f2bf(float f) {
    unsigned u = __float_as_uint(f);
    return (ushort)((u + 0x7fffu + ((u >> 16) & 1u)) >> 16);
}

// packed pair convert: low 16 = a, high 16 = b (v_cvt_pk_bf16_f32 on gfx950)
static __device__ inline unsigned pk2bf(float a, float b) {
    __hip_bfloat162 h = __float22bfloat162_rn(make_float2(a, b));
    union { __hip_bfloat162 h; unsigned u; } c; c.h = h;
    return c.u;
}

static __device__ inline void async16(const ushort* g, ushort* l) {
    __builtin_amdgcn_global_load_lds((const __attribute__((address_space(1))) void*)g,
                                     (__attribute__((address_space(3))) void*)l, 16, 0, 0);
}

// exchange dst-hi-lanes with src-lo-lanes (v_permlane32_swap_b32)
static __device__ inline void plane32swap(unsigned& a, unsigned& b) {
    asm volatile("v_permlane32_swap_b32 %0, %1" : "+v"(a), "+v"(b));
}

// one launch: convert x and W_qkv fp32 -> bf16
__global__ void cvt2(const float* __restrict__ a, ushort* __restrict__ da, int na,
                     const float* __restrict__ b, ushort* __restrict__ db, int nb) {
    long i = (long)(blockIdx.x * blockDim.x + threadIdx.x) * 4;
    const float* s; ushort* d;
    if (i < na) { s = a + i; d = da + i; }
    else { long j = i - na; if (j >= nb) return; s = b + j; d = db + j; }
    float4 v = *(const float4*)s;
    ushort4 o; o.x = f2bf(v.x); o.y = f2bf(v.y); o.z = f2bf(v.z); o.w = f2bf(v.w);
    *(ushort4*)d = o;
}

// LDS: staging (2x16KB) and epilogue C-tile (32KB) share the same 32KB block
union GemmSmem {
    struct { ushort A[128 * 64]; ushort B[128 * 64]; } st;
    ushort C[128 * 128];   // bf16 C-tile, XOR-swizzled: phys_col = col ^ (8*(row&7))
};

// qkv = x @ W^T. m97 K-loop (unpadded LDS, global_load_lds w=16).
__global__ __launch_bounds__(256) void qkv_gemm(
        const ushort* __restrict__ X, const ushort* __restrict__ W,
        ushort* __restrict__ Qd, ushort* __restrict__ Kd, ushort* __restrict__ Vd) {
    __shared__ GemmSmem sm;
    const int t = threadIdx.x;
    const int lane = t & 63, l15 = lane & 15, quad = lane >> 4;
    const int w = t >> 6, wm = w >> 1, wn = w & 1;
    const int gm = blockIdx.x, gn = blockIdx.y;
    const int srow = t >> 3, scol = (t & 7) * 8;

    f32x4 acc[4][4] = {};

    for (int kt = 0; kt < 16; ++kt) {
        const int k0 = kt * 64;
        __syncthreads();
#pragma unroll
        for (int inst = 0; inst < 4; ++inst) {
            async16(&X[(gm * 128 + inst * 32 + srow) * 1024 + k0 + scol], &sm.st.A[inst * 2048 + t * 8]);
            async16(&W[(gn * 128 + inst * 32 + srow) * 1024 + k0 + scol], &sm.st.B[inst * 2048 + t * 8]);
        }
        __syncthreads();
#pragma unroll
        for (int ks = 0; ks < 2; ++ks) {
            const int kk = ks * 32 + quad * 8;
            bf16x8 af[4], bfr[4];
#pragma unroll
            for (int i = 0; i < 4; ++i) {
                af[i]  = *(const bf16x8*)&sm.st.A[(wm * 64 + i * 16 + l15) * 64 + kk];
                bfr[i] = *(const bf16x8*)&sm.st.B[(wn * 64 + i * 16 + l15) * 64 + kk];
            }
#pragma unroll
            for (int i = 0; i < 4; ++i)
#pragma unroll
                for (int j = 0; j < 4; ++j)
                    acc[i][j] = __builtin_amdgcn_mfma_f32_16x16x32_bf16(af[i], bfr[j], acc[i][j], 0, 0, 0);
        }
    }

    __syncthreads();   // all frag reads done; reuse LDS as C-tile
    const float sc = (gn < 8) ? (0.125f * 1.44269504f) : 1.0f;  // fold softmax scale into Q
#pragma unroll
    for (int i = 0; i < 4; ++i)
#pragma unroll
        for (int reg = 0; reg < 4; ++reg) {
            const int row = wm * 64 + i * 16 + quad * 4 + reg;
            const int sw = (row & 7) * 8;
#pragma unroll
            for (int jp = 0; jp < 4; jp += 2) {
                unsigned u = pk2bf(acc[i][jp][reg] * sc, acc[i][jp + 1][reg] * sc);
                sm.C[row * 128 + ((wn * 64 + jp * 16 + l15) ^ sw)] = (ushort)u;
                sm.C[row * 128 + ((wn * 64 + (jp + 1) * 16 + l15) ^ sw)] = (ushort)(u >> 16);
            }
        }
    __syncthreads();

    const int which = gn >> 3;   // 0=Q 1=K 2=V (uniform per block)
    ushort* dst = (which == 0) ? Qd : ((which == 1) ? Kd : Vd);
    const int rloc = t >> 4, l = t & 15;
#pragma unroll
    for (int pass = 0; pass < 8; ++pass) {
        const int r = pass * 16 + rloc;
        bf16x8 v = *(const bf16x8*)&sm.C[r * 128 + ((l * 8) ^ ((r & 7) * 8))];
        const int ng = gm * 128 + r;
        const int b = ng >> 11, n = ng & 2047;
        const int cl = (gn * 128 + l * 8) & 1023;
        const int h = cl >> 6, hd = cl & 63;
        *(bf16x8*)&dst[(((b * NHEADS + h) * SEQ) + n) * HD + hd] = v;
    }
}

// V [bh][n][hd] -> VT [bh][hd][n], LDS-tiled 64x64
__global__ __launch_bounds__(256) void tr_v(const ushort* __restrict__ src, ushort* __restrict__ dst) {
    __shared__ ushort sT[64][72];
    const int t = threadIdx.x;
    const int bh = blockIdx.y, nt = blockIdx.x;
    const int r0 = t >> 3, c8 = (t & 7) * 8;
    const ushort* sp = src + ((long)bh * SEQ + nt * 64) * HD;
#pragma unroll
    for (int rr = 0; rr < 64; rr += 32)
        *(bf16x8*)&sT[rr + r0][c8] = *(const bf16x8*)&sp[(rr + r0) * HD + c8];
    __syncthreads();
    ushort* dp = dst + (long)bh * HD * SEQ + nt * 64;
#pragma unroll
    for (int rr = 0; rr < 64; rr += 32) {
        const int hd = rr + r0;
        bf16x8 v;
#pragma unroll
        for (int j = 0; j < 8; ++j) v[j] = (short)sT[c8 + j][hd];
        *(bf16x8*)&dp[(long)hd * SEQ + c8] = v;
    }
}

// Flash attention (no-max softmax; logits bounded, scale folded into Q).
// 4 waves x 64 q-rows = 256 q/block; KVBLK=128/iter; each K/V frag ds_read
// feeds TWO MFMAs (both q-half operands register-resident).
// Cross-iteration software pipeline (T15 mechanism): S(kt+1) is computed by
// QK MFMAs at the END of iter kt, placed right after the barrier; its drain
// overlaps iter kt+1's stage-issue + softmax VALU (independent work). PV(kt)
// keeps the matrix pipe fed behind QK. 3-buffer LDS rotation with counted
// s_waitcnt vmcnt(8) (T3/T4: in-flight loads cross the barrier, never drain
// to 0) and ONE barrier per iteration.
// Grid 256 = 1 block/CU, 1 wave/SIMD: all hiding from ILP (launch_bounds(256,1)
// gives the 512-reg budget).
__global__ __launch_bounds__(256, 1) void attn_kernel(
        const ushort* __restrict__ Q, const ushort* __restrict__ K,
        const ushort* __restrict__ VT, float* __restrict__ O) {
    __shared__ ushort sK[3][128 * 64];   // [kv][d]: 128 rows x 128B, swz 16B slots
    __shared__ ushort sVT[3][64 * 128];  // [d][kv]: 64 rows x 256B, swz 16B slots
    __shared__ float sL[4][64];

    const int t = threadIdx.x;
    const int lane = t & 63, l31 = lane & 31, hi = lane >> 5;
    const int w = t >> 6;

    // XCD swizzle: blocks dispatch round-robin by flat id % 8. All 8 q-blocks
    // of one bh share an XCD; each XCD caches 4 bh of K/V (2MB) in its L2.
    const int flat = blockIdx.y * gridDim.x + blockIdx.x;   // 0..255
    const int qt = (flat >> 3) & 7;
    const int bh = (flat & 7) + ((flat >> 6) << 3);

    const ushort* Qp = Q + ((long)bh * SEQ + qt * 256 + w * 64) * HD;
    const ushort* Kp = K + (long)bh * SEQ * HD;
    const ushort* Vp = VT + (long)bh * HD * SEQ;

    // Q fragments, two q-halves (B operand): lane holds Q[q][k=ks*16+hi*8+j]
    bf16x8 bq[2][4];
#pragma unroll
    for (int qh = 0; qh < 2; ++qh)
#pragma unroll
        for (int ks = 0; ks < 4; ++ks)
            bq[qh][ks] = *(const bf16x8*)&Qp[(qh * 32 + l31) * HD + ks * 16 + hi * 8];

    // K staging: chunk c covers rows c*32 + (t>>3); 16B slot t&7 of a 128B row;
    // linear LDS dest, swizzle via pre-swizzled SOURCE column.
    const int krow = t >> 3;                          // 0..31
    const int kcol = ((t & 7) ^ (krow & 7)) * 8;
    const ushort* gK = Kp + krow * HD + kcol;
    // V staging: chunk c covers d-rows c*16 + (t>>4); 16B slot t&15 of a 256B row.
    const int vrow = t >> 4;                          // 0..15
    const int vcol = ((t & 15) ^ (vrow & 7)) * 8;
    const ushort* gV = Vp + (long)vrow * SEQ + vcol;

    // rotating buffer roles (cur, next, far) as named variables (no runtime
    // array indexing -> registers, not scratch)
    ushort* stK0 = &sK[0][t * 8]; ushort* stK1 = &sK[1][t * 8]; ushort* stK2 = &sK[2][t * 8];
    ushort* stV0 = &sVT[0][t * 8]; ushort* stV1 = &sVT[1][t * 8]; ushort* stV2 = &sVT[2][t * 8];
    const ushort* rdK0 = sK[0]; const ushort* rdK1 = sK[1]; const ushort* rdK2 = sK[2];
    const ushort* rdV0 = sVT[0]; const ushort* rdV1 = sVT[1]; const ushort* rdV2 = sVT[2];

    f32x16 accA[2] = {}, accB[2] = {};
    f32x16 sA[4], sB[4];
    bf16x8 paA[8], paB[8];
    f32x4 LpA = {}, LpB = {};
    const int swz = (l31 & 7) << 3;

    auto do_stage = [&](int tile, ushort* dK, ushort* dV) {
        const ushort* nK = gK + (long)tile * 128 * HD;
        const ushort* nV = gV + tile * 128;
#pragma unroll
        for (int c = 0; c < 4; ++c) {
            async16(nK + c * 32 * HD, dK + c * 2048);
            async16(nV + (long)c * 16 * SEQ, dV + c * 2048);
        }
    };

    auto do_qk = [&](const ushort* bK) {
#pragma unroll
        for (int nb = 0; nb < 4; ++nb) {
            f32x16 zA = {}, zB = {};
#pragma unroll
            for (int ks = 0; ks < 4; ++ks) {
                bf16x8 ak = *(const bf16x8*)&bK[(nb * 32 + l31) * 64 + ((ks * 16 + hi * 8) ^ swz)];
                zA = __builtin_amdgcn_mfma_f32_32x32x16_bf16(ak, bq[0][ks], zA, 0, 0, 0);
                zB = __builtin_amdgcn_mfma_f32_32x32x16_bf16(ak, bq[1][ks], zB, 0, 0, 0);
            }
            sA[nb] = zA; sB[nb] = zB;
        }
    };

    // softmax: s -> pa fragments (frees sA/sB for the next QK) + L partials
    auto do_sm = [&]() {
#pragma unroll
        for (int sb = 0; sb < 4; ++sb) {
            float pA[16], pB[16];
#pragma unroll
            for (int r = 0; r < 16; ++r) {
                pA[r] = __builtin_amdgcn_exp2f(sA[sb][r]);
                pB[r] = __builtin_amdgcn_exp2f(sB[sb][r]);
            }
#pragma unroll
            for (int r = 0; r < 16; ++r) { LpA[r & 3] += pA[r]; LpB[r & 3] += pB[r]; }
#pragma unroll
            for (int h2 = 0; h2 < 2; ++h2) {
                const int b = 8 * h2;
                const int flat = (sb >> 1) * 4 + (sb & 1) * 2 + h2;   // = h*4 + ks
                unsigned a0 = pk2bf(pA[b + 0], pA[b + 1]);
                unsigned a1 = pk2bf(pA[b + 2], pA[b + 3]);
                unsigned a2 = pk2bf(pA[b + 4], pA[b + 5]);
                unsigned a3 = pk2bf(pA[b + 6], pA[b + 7]);
                plane32swap(a0, a2);
                plane32swap(a1, a3);
                union { unsigned u[4]; bf16x8 v; } fa;
                fa.u[0] = a0; fa.u[1] = a1; fa.u[2] = a2; fa.u[3] = a3;
                paA[flat] = fa.v;
                unsigned b0 = pk2bf(pB[b + 0], pB[b + 1]);
                unsigned b1 = pk2bf(pB[b + 2], pB[b + 3]);
                unsigned b2 = pk2bf(pB[b + 4], pB[b + 5]);
                unsigned b3 = pk2bf(pB[b + 6], pB[b + 7]);
                plane32swap(b0, b2);
                plane32swap(b1, b3);
                union { unsigned u[4]; bf16x8 v; } fb;
                fb.u[0] = b0; fb.u[1] = b1; fb.u[2] = b2; fb.u[3] = b3;
                paB[flat] = fb.v;
            }
        }
    };

    auto do_pv = [&](const ushort* bV) {
#pragma unroll
        for (int h = 0; h < 2; ++h)
#pragma unroll
            for (int db = 0; db < 2; ++db)
#pragma unroll
                for (int ks = 0; ks < 4; ++ks) {
                    bf16x8 vf = *(const bf16x8*)&bV[(db * 32 + l31) * 128 + h * 64 + ((ks * 16 + hi * 8) ^ swz)];
                    accA[db] = __builtin_amdgcn_mfma_f32_32x32x16_bf16(paA[h * 4 + ks], vf, accA[db], 0, 0, 0);
                    accB[db] = __builtin_amdgcn_mfma_f32_32x32x16_bf16(paB[h * 4 + ks], vf, accB[db], 0, 0, 0);
                }
    };

    // prologue: stage tiles 0,1; wait only for tile 0 (tile 1 stays in flight)
    do_stage(0, stK0, stV0);
    do_stage(1, stK1, stV1);
    asm volatile("s_waitcnt vmcnt(8)" ::: "memory");
    __builtin_amdgcn_s_barrier();
    __builtin_amdgcn_sched_barrier(0);
    do_qk(rdK0);                        // S(0)

    for (int kt = 0; kt < 15; ++kt) {
        int ft = kt + 2; if (ft > 15) ft = 15;   // clamped re-stage keeps vmcnt uniform
        do_stage(ft, stK2, stV2);       // writes far buffer (last read 3 tiles ago)
        do_sm();                        // VALU; overlaps QK(kt)'s MFMA drain
        do_pv(rdV0);                    // MFMA on tile kt
        asm volatile("s_waitcnt vmcnt(8)" ::: "memory");   // tile kt+1 landed; kt+2 in flight
        __builtin_amdgcn_s_barrier();
        __builtin_amdgcn_sched_barrier(0);
        do_qk(rdK1);                    // S(kt+1) from next buffer
        // rotate (cur,next,far) <- (next,far,cur)
        ushort* tk = stK0; stK0 = stK1; stK1 = stK2; stK2 = tk;
        ushort* tv = stV0; stV0 = stV1; stV1 = stV2; stV2 = tv;
        const ushort* rk = rdK0; rdK0 = rdK1; rdK1 = rdK2; rdK2 = rk;
        const ushort* rv = rdV0; rdV0 = rdV1; rdV1 = rdV2; rdV2 = rv;
    }
    // epilogue: tile 15
    do_sm();
    do_pv(rdV0);

    // combine L: 4 ILP partials, then lane <-> lane+32 halves
    {
        const float la = (LpA[0] + LpA[1]) + (LpA[2] + LpA[3]);
        unsigned lu = __float_as_uint(la), lv = lu;
        plane32swap(lu, lv);
        const float lb = (LpB[0] + LpB[1]) + (LpB[2] + LpB[3]);
        unsigned mu = __float_as_uint(lb), mv = mu;
        plane32swap(mu, mv);
        if (hi == 0) {
            sL[w][l31]      = __uint_as_float(lu) + __uint_as_float(lv);
            sL[w][32 + l31] = __uint_as_float(mu) + __uint_as_float(mv);
        }
    }
    __syncthreads();

    const int b = bh >> 4, h = bh & 15;
    const int qg0 = qt * 256 + w * 64;
#pragma unroll
    for (int r = 0; r < 16; ++r) {
        const int ql = (r & 3) + 8 * (r >> 2) + 4 * hi;   // C-row -> q within 32
        const float invA = 1.0f / sL[w][ql];
        const float invB = 1.0f / sL[w][32 + ql];
#pragma unroll
        for (int db = 0; db < 2; ++db) {
            O[((long)b * SEQ + qg0 + ql) * DMODEL + h * HD + db * 32 + l31]      = accA[db][r] * invA;
            O[((long)b * SEQ + qg0 + 32 + ql) * DMODEL + h * HD + db * 32 + l31] = accB[db][r] * invB;
        }
    }
}

extern "C" void kernel_launch(void* const* d_in, const int* in_sizes, int n_in,
                              void* d_out, int out_size, void* d_ws, size_t ws_size,
                              hipStream_t stream) {
    const float* x  = (const float*)d_in[0];   // (2, 2048, 1024) fp32
    const float* Wq = (const float*)d_in[1];   // (3072, 1024) fp32
    float* out = (float*)d_out;                // (2, 2048, 1024) fp32

    const int NX = BATCH * SEQ * DMODEL;        // 4194304
    const int NW = 3 * DMODEL * DMODEL;         // 3145728
    const int NQKV = BATCH * NHEADS * SEQ * HD; // 4194304

    ushort* xb = (ushort*)d_ws;
    ushort* wb = xb + NX;
    ushort* q  = wb + NW;
    ushort* k  = q + NQKV;
    ushort* vtmp = k + NQKV;
    ushort* vt = xb;    // xb is dead after the GEMM; alias it for V^T (same size)

    cvt2<<<(NX + NW) / 4 / 256, 256, 0, stream>>>(x, xb, NX, Wq, wb, NW);

    dim3 g1(4096 / 128, 3072 / 128);   // 32 x 24
    qkv_gemm<<<g1, 256, 0, stream>>>(xb, wb, q, k, vtmp);

    dim3 gt(SEQ / 64, BATCH * NHEADS); // 32 x 32
    tr_v<<<gt, 256, 0, stream>>>(vtmp, vt);

    dim3 g2(SEQ / 256, BATCH * NHEADS); // 8 x 32
    attn_kernel<<<g2, 256, 0, stream>>>(q, k, vt, out);
}